// Round 4
// baseline (762.570 us; speedup 1.0000x reference)
//
#include <hip/hip_runtime.h>
#include <hip/hip_bf16.h>

#define HH 1080
#define WW 1920
#define HWSZ (HH * WW)

typedef __attribute__((ext_vector_type(8))) short bf16x8;
typedef __attribute__((ext_vector_type(4))) float f32x4;
typedef __attribute__((ext_vector_type(4))) short s16x4;

__device__ __forceinline__ float clipf(float x, float lo, float hi) {
    return fminf(fmaxf(x, lo), hi);
}
__device__ __forceinline__ short f2bf(float f) {
    __hip_bfloat16 h = __float2bfloat16(f);
    return *(short*)&h;
}
__device__ __forceinline__ float fpow(float a, float e) {
    return __expf(__logf(a) * e);   // a >= 1e-7 guaranteed by callers
}
__device__ __forceinline__ void pinreg(bf16x8& v) {
    asm volatile("" : "+v"(v));     // keep fragment register-resident
}

// ---------------------------------------------------------------------------
// Kernel 1: classical grade + 3D LUT + blend.
// Writes: xb (planar f32) and xin (NHWC bf16 8ch: x0..2, xb0..2, 0, 0).
// ---------------------------------------------------------------------------
__global__ __launch_bounds__(256) void grade_kernel(
    const float* __restrict__ x, const float* __restrict__ lut,
    const float* __restrict__ cm, const float* __restrict__ cbp,
    const float* __restrict__ shp, const float* __restrict__ mip,
    const float* __restrict__ hip_, const float* __restrict__ cop,
    const float* __restrict__ satp, const float* __restrict__ wap,
    const float* __restrict__ lbp,
    float* __restrict__ xb, __hip_bfloat16* __restrict__ xin)
{
    int i = blockIdx.x * blockDim.x + threadIdx.x;
    if (i >= HWSZ) return;

    float in0 = x[i], in1 = x[HWSZ + i], in2 = x[2 * HWSZ + i];

    float M00 = clipf(cm[0], 0.9f, 1.1f), M01 = clipf(cm[1], 0.9f, 1.1f), M02 = clipf(cm[2], 0.9f, 1.1f);
    float M10 = clipf(cm[3], 0.9f, 1.1f), M11 = clipf(cm[4], 0.9f, 1.1f), M12 = clipf(cm[5], 0.9f, 1.1f);
    float M20 = clipf(cm[6], 0.9f, 1.1f), M21 = clipf(cm[7], 0.9f, 1.1f), M22 = clipf(cm[8], 0.9f, 1.1f);
    float bi0 = clipf(cbp[0], -0.02f, 0.02f);
    float bi1 = clipf(cbp[1], -0.02f, 0.02f);
    float bi2 = clipf(cbp[2], -0.02f, 0.02f);

    float sh  = clipf(shp[0], -0.02f, 0.05f);
    float mi  = clipf(mip[0], 0.95f, 1.05f);
    float hi  = clipf(hip_[0], 0.95f, 1.05f);
    float co  = clipf(cop[0], 0.98f, 1.05f);
    float sat = clipf(satp[0], 0.95f, 1.3f);
    float wa  = clipf(wap[0], -0.02f, 0.05f);
    float lb  = clipf(lbp[0], 0.7f, 0.9f);

    float xc[3];
    xc[0] = M00 * in0 + M01 * in1 + M02 * in2 + bi0;
    xc[1] = M10 * in0 + M11 * in1 + M12 * in2 + bi1;
    xc[2] = M20 * in0 + M21 * in1 + M22 * in2 + bi2;

    float inv_mi = 1.0f / mi, inv_co = 1.0f / co;
    float xg[3];
#pragma unroll
    for (int c = 0; c < 3; c++) {
        float v = xc[c];
        float sm = clipf(1.f - v, 0.f, 1.f);
        sm = sm * sm * sm;
        float xs = v + sh * sm * (1.f - v) * 0.5f;
        float xm = fpow(clipf(xs, 1e-7f, 1.f), inv_mi);
        float hm = clipf(xm, 0.f, 1.f);
        hm = hm * hm * hm;
        float x2 = clipf(xm * (1.f - hm * (1.f - hi) * 0.5f), 0.f, 1.f);
        xg[c] = fpow(clipf(x2, 1e-7f, 1.f), inv_co);
    }

    float luma = 0.299f * xg[0] + 0.587f * xg[1] + 0.114f * xg[2];
    float s0 = luma + sat * (xg[0] - luma);
    float s1 = luma + sat * (xg[1] - luma);
    float s2 = luma + sat * (xg[2] - luma);

    float pr = clipf(s0 * (1.f + wa), 0.f, 1.f);
    float pg = clipf(s1 * (1.f + wa * 0.3f), 0.f, 1.f);
    float pb = clipf(s2 * (1.f - wa * 0.5f), 0.f, 1.f);

    float cr = pr * 32.f, cg = pg * 32.f, cb2 = pb * 32.f;
    float fr = floorf(cr), fgq = floorf(cg), fb = floorf(cb2);
    float fx = cr - fr, fy = cg - fgq, fz = cb2 - fb;
    int x0 = min(max((int)fr, 0), 31);
    int y0 = min(max((int)fgq, 0), 31);
    int z0 = min(max((int)fb, 0), 31);

    const float* base = lut + ((x0 * 33 + y0) * 33 + z0) * 3;
    float pcl[3] = {pr, pg, pb};
    float bl[3];
#pragma unroll
    for (int ch = 0; ch < 3; ch++) {
        float c000 = base[ch];
        float c001 = base[3 + ch];
        float c010 = base[99 + ch];
        float c011 = base[102 + ch];
        float c100 = base[3267 + ch];
        float c101 = base[3270 + ch];
        float c110 = base[3366 + ch];
        float c111 = base[3369 + ch];
        float c00 = c000 * (1.f - fx) + c100 * fx;
        float c01 = c001 * (1.f - fx) + c101 * fx;
        float c10 = c010 * (1.f - fx) + c110 * fx;
        float c11 = c011 * (1.f - fx) + c111 * fx;
        float c0 = c00 * (1.f - fy) + c10 * fy;
        float c1 = c01 * (1.f - fy) + c11 * fy;
        float lv = c0 * (1.f - fz) + c1 * fz;
        bl[ch] = lb * lv + (1.f - lb) * pcl[ch];
        xb[(size_t)ch * HWSZ + i] = bl[ch];
    }

    bf16x8 xi;
    xi[0] = f2bf(in0); xi[1] = f2bf(in1); xi[2] = f2bf(in2);
    xi[3] = f2bf(bl[0]); xi[4] = f2bf(bl[1]); xi[5] = f2bf(bl[2]);
    xi[6] = 0; xi[7] = 0;
    *(bf16x8*)(xin + (size_t)i * 8) = xi;
}

// ---------------------------------------------------------------------------
// Implicit-GEMM MFMA conv, NHWC bf16, K ordered tap-major (k = tap*CI + ci).
// Weight fragments (BN-folded) register-resident (launch_bounds(256,2) +
// pinreg); B fragments double-buffered across 16-px tiles (explicit SW
// pipeline; named buffers, static indexing only).
// ---------------------------------------------------------------------------
template <int CI, int CIR, int COUTB, int COUTR, int NG, bool FINAL>
__global__ __launch_bounds__(256, 2) void conv_mfma(
    const __hip_bfloat16* __restrict__ in, int in_y0, int in_rows,
    const float* __restrict__ w, const float* __restrict__ w2,
    const float* __restrict__ bg, const float* __restrict__ bb,
    const float* __restrict__ bm, const float* __restrict__ bv,
    __hip_bfloat16* __restrict__ out, int out_y0, int out_rows,
    const float* __restrict__ xb, const float* __restrict__ stp,
    float* __restrict__ fout)
{
    constexpr int COUT = COUTB * 16;
    constexpr int SEGW = 192;
    constexpr int NT   = SEGW / 16;   // 12, even

    int l    = threadIdx.x & 63;
    int wv   = threadIdx.x >> 6;
    int lrow = blockIdx.y * 4 + wv;
    if (lrow >= out_rows) return;
    int y    = out_y0 + lrow;
    int x0   = blockIdx.x * SEGW;
    int mrow = l & 15;
    int sub  = l >> 4;

    // Accumulator init: BN offset / bias for this lane's output rows.
    f32x4 ainit[COUTB];
#pragma unroll
    for (int cb = 0; cb < COUTB; cb++) {
#pragma unroll
        for (int r = 0; r < 4; r++) {
            int c = cb * 16 + sub * 4 + r;
            float v = 0.f;
            if (FINAL) {
                v = (c < 3) ? bb[c] : (c == 3 ? bm[0] : 0.f);
            } else if (c < COUTR) {
                float s = bg[c] * rsqrtf(bv[c] + 1e-5f);
                v = bb[c] - bm[c] * s;
            }
            ainit[cb][r] = v;
        }
    }

    float stv = 0.f;
    if (FINAL) stv = clipf(stp[0], 0.02f, 0.2f);

    // Weight fragments (BN scale folded). rowM = cb*16 + mrow.
    bf16x8 wf[COUTB][NG];
#pragma unroll
    for (int cb = 0; cb < COUTB; cb++) {
        int cout = cb * 16 + mrow;
        float scl = 1.f;
        if (!FINAL)
            scl = (cout < COUTR) ? bg[cout] * rsqrtf(bv[cout] + 1e-5f) : 0.f;
#pragma unroll
        for (int g = 0; g < NG; g++) {
            bf16x8 f;
#pragma unroll
            for (int j = 0; j < 8; j++) {
                int k   = g * 32 + sub * 8 + j;
                int tap = k / CI;
                int ci  = k % CI;
                float val = 0.f;
                if (tap < 9 && ci < CIR && cout < COUTR) {
                    if (FINAL)
                        val = (cout < 3) ? w[(cout * CIR + ci) * 9 + tap]
                                         : w2[ci * 9 + tap];
                    else
                        val = w[(cout * CIR + ci) * 9 + tap] * scl;
                }
                f[j] = f2bf(val);
            }
            wf[cb][g] = f;
            pinreg(wf[cb][g]);
        }
    }

    // Per-group geometry (fixed per lane).
    const __hip_bfloat16* baseg[NG];
    int dxg[NG];
    bool okg[NG];
#pragma unroll
    for (int g = 0; g < NG; g++) {
        int kl  = g * 32 + sub * 8;
        int tap = kl / CI;
        int cib = kl % CI;
        int dy = (tap < 9) ? tap / 3 - 1 : 0;
        int dx = (tap < 9) ? tap % 3 - 1 : 0;
        int yy = y + dy;
        okg[g] = (yy >= 0 && yy < HH);
        baseg[g] = in + ((long)(yy - in_y0) * WW + dx) * CI + cib;
        dxg[g] = dx;
    }

#define LOADB(t, buf)                                                        \
    do {                                                                     \
        int xp_ = x0 + (t) * 16 + mrow;                                      \
        _Pragma("unroll")                                                    \
        for (int g = 0; g < NG; g++) {                                       \
            int xx_ = xp_ + dxg[g];                                          \
            bf16x8 v_ = {0, 0, 0, 0, 0, 0, 0, 0};                            \
            if (okg[g] && (unsigned)xx_ < (unsigned)WW)                      \
                v_ = *(const bf16x8*)(baseg[g] + (size_t)xp_ * CI);          \
            buf[g] = v_;                                                     \
        }                                                                    \
    } while (0)

#define COMPUTE(t, buf)                                                      \
    do {                                                                     \
        int xp_ = x0 + (t) * 16 + mrow;                                      \
        f32x4 acc[COUTB];                                                    \
        _Pragma("unroll")                                                    \
        for (int cb = 0; cb < COUTB; cb++) acc[cb] = ainit[cb];              \
        _Pragma("unroll")                                                    \
        for (int g = 0; g < NG; g++) {                                       \
            _Pragma("unroll")                                                \
            for (int cb = 0; cb < COUTB; cb++)                               \
                acc[cb] = __builtin_amdgcn_mfma_f32_16x16x32_bf16(           \
                    wf[cb][g], buf[g], acc[cb], 0, 0, 0);                    \
        }                                                                    \
        if constexpr (!FINAL) {                                              \
            _Pragma("unroll")                                                \
            for (int cb = 0; cb < COUTB; cb++) {                             \
                s16x4 s_;                                                    \
                _Pragma("unroll")                                            \
                for (int r = 0; r < 4; r++)                                  \
                    s_[r] = f2bf(fmaxf(acc[cb][r], 0.f));                    \
                *(s16x4*)(out + ((size_t)lrow * WW + xp_) * COUT +           \
                          cb * 16 + sub * 4) = s_;                           \
            }                                                                \
        } else {                                                             \
            if (sub == 0) {                                                  \
                float at_ = 1.f / (1.f + __expf(-acc[0][3]));                \
                size_t gi_ = (size_t)y * WW + xp_;                           \
                _Pragma("unroll")                                            \
                for (int c = 0; c < 3; c++) {                                \
                    float rs_ = tanhf(acc[0][c]);                            \
                    fout[(size_t)c * HWSZ + gi_] = clipf(                    \
                        xb[(size_t)c * HWSZ + gi_] + stv * rs_ * at_,        \
                        0.f, 1.f);                                           \
                }                                                            \
            }                                                                \
        }                                                                    \
    } while (0)

    bf16x8 bufA[NG], bufB[NG];
    LOADB(0, bufA);
#pragma unroll
    for (int tt = 0; tt < NT; tt += 2) {
        LOADB(tt + 1, bufB);
        COMPUTE(tt, bufA);
        if (tt + 2 < NT) LOADB(tt + 2, bufA);
        COMPUTE(tt + 1, bufB);
    }
#undef LOADB
#undef COMPUTE
}

// ---------------------------------------------------------------------------
extern "C" void kernel_launch(void* const* d_in, const int* in_sizes, int n_in,
                              void* d_out, int out_size, void* d_ws, size_t ws_size,
                              hipStream_t stream)
{
    const float* x   = (const float*)d_in[0];
    const float* lut = (const float*)d_in[1];
    const float* cm  = (const float*)d_in[2];
    const float* cb  = (const float*)d_in[3];
    const float* sh  = (const float*)d_in[4];
    const float* mi  = (const float*)d_in[5];
    const float* hi  = (const float*)d_in[6];
    const float* co  = (const float*)d_in[7];
    const float* sa  = (const float*)d_in[8];
    const float* wa  = (const float*)d_in[9];
    const float* lb  = (const float*)d_in[10];
    const float* st  = (const float*)d_in[11];
    const float* w1  = (const float*)d_in[12];
    const float* g1  = (const float*)d_in[13];
    const float* b1  = (const float*)d_in[14];
    const float* m1  = (const float*)d_in[15];
    const float* v1  = (const float*)d_in[16];
    const float* w2  = (const float*)d_in[17];
    const float* g2  = (const float*)d_in[18];
    const float* b2  = (const float*)d_in[19];
    const float* m2  = (const float*)d_in[20];
    const float* v2  = (const float*)d_in[21];
    const float* w3  = (const float*)d_in[22];
    const float* g3  = (const float*)d_in[23];
    const float* b3  = (const float*)d_in[24];
    const float* m3  = (const float*)d_in[25];
    const float* v3  = (const float*)d_in[26];
    const float* rw  = (const float*)d_in[27];
    const float* rb  = (const float*)d_in[28];
    const float* aw  = (const float*)d_in[29];
    const float* ab  = (const float*)d_in[30];

    // Workspace (~192 MB): xb f32 24.9 | xin bf16 33.2 | f1 66.7 | f2 66.7
    char* ws = (char*)d_ws;
    const size_t XB_BYTES  = (size_t)3 * HWSZ * sizeof(float);
    const size_t XIN_BYTES = (size_t)8 * HWSZ * sizeof(__hip_bfloat16);
    const size_t F_BYTES   = (size_t)32 * 543 * WW * sizeof(__hip_bfloat16);
    float* xb = (float*)ws;
    __hip_bfloat16* xin = (__hip_bfloat16*)(ws + XB_BYTES);
    __hip_bfloat16* f1  = (__hip_bfloat16*)(ws + XB_BYTES + XIN_BYTES);
    __hip_bfloat16* f2  = (__hip_bfloat16*)(ws + XB_BYTES + XIN_BYTES + F_BYTES);
    __hip_bfloat16* f3  = f1;   // f1 dead once conv2 of this half is done

    {
        int grid = (HWSZ + 255) / 256;
        grade_kernel<<<grid, 256, 0, stream>>>(x, lut, cm, cb, sh, mi, hi, co,
                                               sa, wa, lb, xb, xin);
    }

    for (int h = 0; h < 2; h++) {
        int r0 = (h == 0) ? 0 : HH / 2;
        int r1 = (h == 0) ? HH / 2 : HH;

        int f1_y0 = max(r0 - 3, 0), f1_y1 = min(r1 + 3, HH);
        int f2_y0 = max(r0 - 2, 0), f2_y1 = min(r1 + 2, HH);
        int f3_y0 = max(r0 - 1, 0), f3_y1 = min(r1 + 1, HH);
        int f1_rows = f1_y1 - f1_y0;
        int f2_rows = f2_y1 - f2_y0;
        int f3_rows = f3_y1 - f3_y0;
        int out_rows = r1 - r0;

        dim3 blk(256);
        dim3 gr1(10, (f1_rows + 3) / 4);
        dim3 gr2(10, (f2_rows + 3) / 4);
        dim3 gr3(10, (f3_rows + 3) / 4);
        dim3 gr4(10, (out_rows + 3) / 4);

        // conv1: 6(->8 padded) -> 32, K=96 (12 taps, 3 zero)
        conv_mfma<8, 6, 2, 32, 3, false><<<gr1, blk, 0, stream>>>(
            xin, 0, HH, w1, nullptr, g1, b1, m1, v1,
            f1, f1_y0, f1_rows, nullptr, nullptr, nullptr);
        // conv2: 32 -> 32, K=288
        conv_mfma<32, 32, 2, 32, 9, false><<<gr2, blk, 0, stream>>>(
            f1, f1_y0, f1_rows, w2, nullptr, g2, b2, m2, v2,
            f2, f2_y0, f2_rows, nullptr, nullptr, nullptr);
        // conv3: 32 -> 16, K=288
        conv_mfma<32, 32, 1, 16, 9, false><<<gr3, blk, 0, stream>>>(
            f2, f2_y0, f2_rows, w3, nullptr, g3, b3, m3, v3,
            f3, f3_y0, f3_rows, nullptr, nullptr, nullptr);
        // final: 16 -> 4 (res0-2 + attn), K=160 (10 taps, 1 zero), fused blend
        conv_mfma<16, 16, 1, 4, 5, true><<<gr4, blk, 0, stream>>>(
            f3, f3_y0, f3_rows, rw, aw, rb, rb, ab, ab,
            nullptr, r0, out_rows, xb, st, (float*)d_out);
    }
}

// Round 5
// 455.162 us; speedup vs baseline: 1.6754x; 1.6754x over previous
//
#include <hip/hip_runtime.h>
#include <hip/hip_bf16.h>

#define HH 1080
#define WW 1920
#define HWSZ (HH * WW)

typedef __attribute__((ext_vector_type(8))) short bf16x8;
typedef __attribute__((ext_vector_type(4))) float f32x4;
typedef __attribute__((ext_vector_type(4))) short s16x4;

__device__ __forceinline__ float clipf(float x, float lo, float hi) {
    return fminf(fmaxf(x, lo), hi);
}
__device__ __forceinline__ short f2bf(float f) {
    __hip_bfloat16 h = __float2bfloat16(f);
    return *(short*)&h;
}
__device__ __forceinline__ float fpow(float a, float e) {
    return __expf(__logf(a) * e);   // a >= 1e-7 guaranteed by callers
}

// ---------------------------------------------------------------------------
// Kernel 1: classical grade + 3D LUT + blend.
// Writes: xb (planar f32) and xin (NHWC bf16 8ch: x0..2, xb0..2, 0, 0).
// ---------------------------------------------------------------------------
__global__ __launch_bounds__(256) void grade_kernel(
    const float* __restrict__ x, const float* __restrict__ lut,
    const float* __restrict__ cm, const float* __restrict__ cbp,
    const float* __restrict__ shp, const float* __restrict__ mip,
    const float* __restrict__ hip_, const float* __restrict__ cop,
    const float* __restrict__ satp, const float* __restrict__ wap,
    const float* __restrict__ lbp,
    float* __restrict__ xb, __hip_bfloat16* __restrict__ xin)
{
    int i = blockIdx.x * blockDim.x + threadIdx.x;
    if (i >= HWSZ) return;

    float in0 = x[i], in1 = x[HWSZ + i], in2 = x[2 * HWSZ + i];

    float M00 = clipf(cm[0], 0.9f, 1.1f), M01 = clipf(cm[1], 0.9f, 1.1f), M02 = clipf(cm[2], 0.9f, 1.1f);
    float M10 = clipf(cm[3], 0.9f, 1.1f), M11 = clipf(cm[4], 0.9f, 1.1f), M12 = clipf(cm[5], 0.9f, 1.1f);
    float M20 = clipf(cm[6], 0.9f, 1.1f), M21 = clipf(cm[7], 0.9f, 1.1f), M22 = clipf(cm[8], 0.9f, 1.1f);
    float bi0 = clipf(cbp[0], -0.02f, 0.02f);
    float bi1 = clipf(cbp[1], -0.02f, 0.02f);
    float bi2 = clipf(cbp[2], -0.02f, 0.02f);

    float sh  = clipf(shp[0], -0.02f, 0.05f);
    float mi  = clipf(mip[0], 0.95f, 1.05f);
    float hi  = clipf(hip_[0], 0.95f, 1.05f);
    float co  = clipf(cop[0], 0.98f, 1.05f);
    float sat = clipf(satp[0], 0.95f, 1.3f);
    float wa  = clipf(wap[0], -0.02f, 0.05f);
    float lb  = clipf(lbp[0], 0.7f, 0.9f);

    float xc[3];
    xc[0] = M00 * in0 + M01 * in1 + M02 * in2 + bi0;
    xc[1] = M10 * in0 + M11 * in1 + M12 * in2 + bi1;
    xc[2] = M20 * in0 + M21 * in1 + M22 * in2 + bi2;

    float inv_mi = 1.0f / mi, inv_co = 1.0f / co;
    float xg[3];
#pragma unroll
    for (int c = 0; c < 3; c++) {
        float v = xc[c];
        float sm = clipf(1.f - v, 0.f, 1.f);
        sm = sm * sm * sm;
        float xs = v + sh * sm * (1.f - v) * 0.5f;
        float xm = fpow(clipf(xs, 1e-7f, 1.f), inv_mi);
        float hm = clipf(xm, 0.f, 1.f);
        hm = hm * hm * hm;
        float x2 = clipf(xm * (1.f - hm * (1.f - hi) * 0.5f), 0.f, 1.f);
        xg[c] = fpow(clipf(x2, 1e-7f, 1.f), inv_co);
    }

    float luma = 0.299f * xg[0] + 0.587f * xg[1] + 0.114f * xg[2];
    float s0 = luma + sat * (xg[0] - luma);
    float s1 = luma + sat * (xg[1] - luma);
    float s2 = luma + sat * (xg[2] - luma);

    float pr = clipf(s0 * (1.f + wa), 0.f, 1.f);
    float pg = clipf(s1 * (1.f + wa * 0.3f), 0.f, 1.f);
    float pb = clipf(s2 * (1.f - wa * 0.5f), 0.f, 1.f);

    float cr = pr * 32.f, cg = pg * 32.f, cb2 = pb * 32.f;
    float fr = floorf(cr), fgq = floorf(cg), fb = floorf(cb2);
    float fx = cr - fr, fy = cg - fgq, fz = cb2 - fb;
    int x0 = min(max((int)fr, 0), 31);
    int y0 = min(max((int)fgq, 0), 31);
    int z0 = min(max((int)fb, 0), 31);

    const float* base = lut + ((x0 * 33 + y0) * 33 + z0) * 3;
    float pcl[3] = {pr, pg, pb};
    float bl[3];
#pragma unroll
    for (int ch = 0; ch < 3; ch++) {
        float c000 = base[ch];
        float c001 = base[3 + ch];
        float c010 = base[99 + ch];
        float c011 = base[102 + ch];
        float c100 = base[3267 + ch];
        float c101 = base[3270 + ch];
        float c110 = base[3366 + ch];
        float c111 = base[3369 + ch];
        float c00 = c000 * (1.f - fx) + c100 * fx;
        float c01 = c001 * (1.f - fx) + c101 * fx;
        float c10 = c010 * (1.f - fx) + c110 * fx;
        float c11 = c011 * (1.f - fx) + c111 * fx;
        float c0 = c00 * (1.f - fy) + c10 * fy;
        float c1 = c01 * (1.f - fy) + c11 * fy;
        float lv = c0 * (1.f - fz) + c1 * fz;
        bl[ch] = lb * lv + (1.f - lb) * pcl[ch];
        xb[(size_t)ch * HWSZ + i] = bl[ch];
    }

    bf16x8 xi;
    xi[0] = f2bf(in0); xi[1] = f2bf(in1); xi[2] = f2bf(in2);
    xi[3] = f2bf(bl[0]); xi[4] = f2bf(bl[1]); xi[5] = f2bf(bl[2]);
    xi[6] = 0; xi[7] = 0;
    *(bf16x8*)(xin + (size_t)i * 8) = xi;
}

// ---------------------------------------------------------------------------
// Pack kernel: fold BN into weights, emit per-lane MFMA A-fragments + acc-init.
// wp layout: frag (cb,g), lane l -> wp[((cb*NG+g)*64 + l)*8 + j]   (bf16)
// ap layout: (cb, lane l)       -> ap[(cb*64 + l)*4 + r]           (f32)
// ---------------------------------------------------------------------------
template <int CI, int CIR, int COUTB, int COUTR, int NG, bool FINAL>
__global__ __launch_bounds__(256) void pack_weights(
    const float* __restrict__ w, const float* __restrict__ w2,
    const float* __restrict__ bg, const float* __restrict__ bb,
    const float* __restrict__ bm, const float* __restrict__ bv,
    short* __restrict__ wp, float* __restrict__ ap)
{
    int t = blockIdx.x * blockDim.x + threadIdx.x;
    constexpr int NFRAG = COUTB * NG * 64;
    if (t < NFRAG) {
        int l    = t & 63;
        int frag = t >> 6;
        int g    = frag % NG;
        int cbk  = frag / NG;
        int mrow = l & 15;
        int sub  = l >> 4;
        int cout = cbk * 16 + mrow;
        float scl = 1.f;
        if (!FINAL)
            scl = (cout < COUTR) ? bg[cout] * rsqrtf(bv[cout] + 1e-5f) : 0.f;
        bf16x8 f;
#pragma unroll
        for (int j = 0; j < 8; j++) {
            int k   = g * 32 + sub * 8 + j;
            int tap = k / CI;
            int ci  = k % CI;
            float val = 0.f;
            if (tap < 9 && ci < CIR && cout < COUTR) {
                if (FINAL)
                    val = (cout < 3) ? w[(cout * CIR + ci) * 9 + tap]
                                     : w2[ci * 9 + tap];
                else
                    val = w[(cout * CIR + ci) * 9 + tap] * scl;
            }
            f[j] = f2bf(val);
        }
        *(bf16x8*)(wp + (size_t)t * 8) = f;
    } else if (t < NFRAG + COUTB * 64) {
        int u   = t - NFRAG;
        int l   = u & 63;
        int cbk = u >> 6;
        int sub = l >> 4;
        f32x4 a;
#pragma unroll
        for (int r = 0; r < 4; r++) {
            int c = cbk * 16 + sub * 4 + r;
            float v = 0.f;
            if (FINAL) {
                v = (c < 3) ? bb[c] : (c == 3 ? bm[0] : 0.f);
            } else if (c < COUTR) {
                float s = bg[c] * rsqrtf(bv[c] + 1e-5f);
                v = bb[c] - bm[c] * s;
            }
            a[r] = v;
        }
        *(f32x4*)(ap + (size_t)u * 4) = a;
    }
}

// ---------------------------------------------------------------------------
// Implicit-GEMM MFMA conv, NHWC bf16, K tap-major (k = tap*CI + ci).
// Weights/acc-init loaded pre-packed (few dwordx4s). B fragments double-
// buffered across 16-px tiles (named buffers, static indexing only).
// ---------------------------------------------------------------------------
template <int CI, int COUTB, int NG, bool FINAL>
__global__ __launch_bounds__(256, 2) void conv_mfma(
    const __hip_bfloat16* __restrict__ in, int in_y0, int in_rows,
    const short* __restrict__ wp, const float* __restrict__ ap,
    __hip_bfloat16* __restrict__ out, int out_y0, int out_rows,
    const float* __restrict__ xb, const float* __restrict__ stp,
    float* __restrict__ fout)
{
    constexpr int COUT = COUTB * 16;
    constexpr int SEGW = 192;
    constexpr int NT   = SEGW / 16;   // 12, even

    int l    = threadIdx.x & 63;
    int wv   = threadIdx.x >> 6;
    int lrow = blockIdx.y * 4 + wv;
    if (lrow >= out_rows) return;
    int y    = out_y0 + lrow;
    int x0   = blockIdx.x * SEGW;
    int mrow = l & 15;
    int sub  = l >> 4;

    // Load packed acc-init and weight fragments (coalesced dwordx4 loads).
    f32x4 ainit[COUTB];
#pragma unroll
    for (int cbk = 0; cbk < COUTB; cbk++)
        ainit[cbk] = *(const f32x4*)(ap + ((size_t)cbk * 64 + l) * 4);

    bf16x8 wf[COUTB][NG];
#pragma unroll
    for (int cbk = 0; cbk < COUTB; cbk++)
#pragma unroll
        for (int g = 0; g < NG; g++)
            wf[cbk][g] = *(const bf16x8*)(wp + ((size_t)(cbk * NG + g) * 64 + l) * 8);

    float stv = 0.f;
    if (FINAL) stv = clipf(stp[0], 0.02f, 0.2f);

    // Per-group geometry (fixed per lane).
    const __hip_bfloat16* baseg[NG];
    int dxg[NG];
    bool okg[NG];
#pragma unroll
    for (int g = 0; g < NG; g++) {
        int kl  = g * 32 + sub * 8;
        int tap = kl / CI;
        int cib = kl % CI;
        int dy = (tap < 9) ? tap / 3 - 1 : 0;
        int dx = (tap < 9) ? tap % 3 - 1 : 0;
        int yy = y + dy;
        okg[g] = (yy >= 0 && yy < HH);
        baseg[g] = in + ((long)(yy - in_y0) * WW + dx) * CI + cib;
        dxg[g] = dx;
    }

#define LOADB(t, buf)                                                        \
    do {                                                                     \
        int xp_ = x0 + (t) * 16 + mrow;                                      \
        _Pragma("unroll")                                                    \
        for (int g = 0; g < NG; g++) {                                       \
            int xx_ = xp_ + dxg[g];                                          \
            bf16x8 v_ = {0, 0, 0, 0, 0, 0, 0, 0};                            \
            if (okg[g] && (unsigned)xx_ < (unsigned)WW)                      \
                v_ = *(const bf16x8*)(baseg[g] + (size_t)xp_ * CI);          \
            buf[g] = v_;                                                     \
        }                                                                    \
    } while (0)

#define COMPUTE(t, buf)                                                      \
    do {                                                                     \
        int xp_ = x0 + (t) * 16 + mrow;                                      \
        f32x4 acc[COUTB];                                                    \
        _Pragma("unroll")                                                    \
        for (int cbk = 0; cbk < COUTB; cbk++) acc[cbk] = ainit[cbk];         \
        _Pragma("unroll")                                                    \
        for (int g = 0; g < NG; g++) {                                       \
            _Pragma("unroll")                                                \
            for (int cbk = 0; cbk < COUTB; cbk++)                            \
                acc[cbk] = __builtin_amdgcn_mfma_f32_16x16x32_bf16(          \
                    wf[cbk][g], buf[g], acc[cbk], 0, 0, 0);                  \
        }                                                                    \
        if constexpr (!FINAL) {                                              \
            _Pragma("unroll")                                                \
            for (int cbk = 0; cbk < COUTB; cbk++) {                          \
                s16x4 s_;                                                    \
                _Pragma("unroll")                                            \
                for (int r = 0; r < 4; r++)                                  \
                    s_[r] = f2bf(fmaxf(acc[cbk][r], 0.f));                   \
                *(s16x4*)(out + ((size_t)lrow * WW + xp_) * COUT +           \
                          cbk * 16 + sub * 4) = s_;                          \
            }                                                                \
        } else {                                                             \
            if (sub == 0) {                                                  \
                float at_ = 1.f / (1.f + __expf(-acc[0][3]));                \
                size_t gi_ = (size_t)y * WW + xp_;                           \
                _Pragma("unroll")                                            \
                for (int c = 0; c < 3; c++) {                                \
                    float rs_ = tanhf(acc[0][c]);                            \
                    fout[(size_t)c * HWSZ + gi_] = clipf(                    \
                        xb[(size_t)c * HWSZ + gi_] + stv * rs_ * at_,        \
                        0.f, 1.f);                                           \
                }                                                            \
            }                                                                \
        }                                                                    \
    } while (0)

    bf16x8 bufA[NG], bufB[NG];
    LOADB(0, bufA);
#pragma unroll
    for (int tt = 0; tt < NT; tt += 2) {
        LOADB(tt + 1, bufB);
        COMPUTE(tt, bufA);
        if (tt + 2 < NT) LOADB(tt + 2, bufA);
        COMPUTE(tt + 1, bufB);
    }
#undef LOADB
#undef COMPUTE
}

// ---------------------------------------------------------------------------
extern "C" void kernel_launch(void* const* d_in, const int* in_sizes, int n_in,
                              void* d_out, int out_size, void* d_ws, size_t ws_size,
                              hipStream_t stream)
{
    const float* x   = (const float*)d_in[0];
    const float* lut = (const float*)d_in[1];
    const float* cm  = (const float*)d_in[2];
    const float* cb  = (const float*)d_in[3];
    const float* sh  = (const float*)d_in[4];
    const float* mi  = (const float*)d_in[5];
    const float* hi  = (const float*)d_in[6];
    const float* co  = (const float*)d_in[7];
    const float* sa  = (const float*)d_in[8];
    const float* wa  = (const float*)d_in[9];
    const float* lb  = (const float*)d_in[10];
    const float* st  = (const float*)d_in[11];
    const float* w1  = (const float*)d_in[12];
    const float* g1  = (const float*)d_in[13];
    const float* b1  = (const float*)d_in[14];
    const float* m1  = (const float*)d_in[15];
    const float* v1  = (const float*)d_in[16];
    const float* w2  = (const float*)d_in[17];
    const float* g2  = (const float*)d_in[18];
    const float* b2  = (const float*)d_in[19];
    const float* m2  = (const float*)d_in[20];
    const float* v2  = (const float*)d_in[21];
    const float* w3  = (const float*)d_in[22];
    const float* g3  = (const float*)d_in[23];
    const float* b3  = (const float*)d_in[24];
    const float* m3  = (const float*)d_in[25];
    const float* v3  = (const float*)d_in[26];
    const float* rw  = (const float*)d_in[27];
    const float* rb  = (const float*)d_in[28];
    const float* aw  = (const float*)d_in[29];
    const float* ab  = (const float*)d_in[30];

    // Workspace: xb f32 24.9MB | xin bf16 33.2MB | f1 66.7MB | f2 66.7MB | packs ~46KB
    char* ws = (char*)d_ws;
    const size_t XB_BYTES  = (size_t)3 * HWSZ * sizeof(float);
    const size_t XIN_BYTES = (size_t)8 * HWSZ * sizeof(__hip_bfloat16);
    const size_t F_BYTES   = (size_t)32 * 543 * WW * sizeof(__hip_bfloat16);
    float* xb = (float*)ws;
    __hip_bfloat16* xin = (__hip_bfloat16*)(ws + XB_BYTES);
    __hip_bfloat16* f1  = (__hip_bfloat16*)(ws + XB_BYTES + XIN_BYTES);
    __hip_bfloat16* f2  = (__hip_bfloat16*)(ws + XB_BYTES + XIN_BYTES + F_BYTES);
    __hip_bfloat16* f3  = f1;   // f1 dead once conv2 of this half is done

    char* pk = ws + XB_BYTES + XIN_BYTES + 2 * F_BYTES;
    short* wp1 = (short*)(pk);               // 2*3*64*16 = 6144 B
    float* ap1 = (float*)(pk + 6144);        // 2048 B
    short* wp2 = (short*)(pk + 8192);        // 2*9*64*16 = 18432 B
    float* ap2 = (float*)(pk + 26624);       // 2048 B
    short* wp3 = (short*)(pk + 28672);       // 1*9*64*16 = 9216 B
    float* ap3 = (float*)(pk + 37888);       // 1024 B
    short* wp4 = (short*)(pk + 38912);       // 1*5*64*16 = 5120 B
    float* ap4 = (float*)(pk + 44032);       // 1024 B

    // Pack folded weights once (tiny kernels).
    pack_weights<8, 6, 2, 32, 3, false><<<2, 256, 0, stream>>>(
        w1, nullptr, g1, b1, m1, v1, wp1, ap1);
    pack_weights<32, 32, 2, 32, 9, false><<<5, 256, 0, stream>>>(
        w2, nullptr, g2, b2, m2, v2, wp2, ap2);
    pack_weights<32, 32, 1, 16, 9, false><<<3, 256, 0, stream>>>(
        w3, nullptr, g3, b3, m3, v3, wp3, ap3);
    pack_weights<16, 16, 1, 4, 5, true><<<2, 256, 0, stream>>>(
        rw, aw, rb, rb, ab, ab, wp4, ap4);

    {
        int grid = (HWSZ + 255) / 256;
        grade_kernel<<<grid, 256, 0, stream>>>(x, lut, cm, cb, sh, mi, hi, co,
                                               sa, wa, lb, xb, xin);
    }

    for (int h = 0; h < 2; h++) {
        int r0 = (h == 0) ? 0 : HH / 2;
        int r1 = (h == 0) ? HH / 2 : HH;

        int f1_y0 = max(r0 - 3, 0), f1_y1 = min(r1 + 3, HH);
        int f2_y0 = max(r0 - 2, 0), f2_y1 = min(r1 + 2, HH);
        int f3_y0 = max(r0 - 1, 0), f3_y1 = min(r1 + 1, HH);
        int f1_rows = f1_y1 - f1_y0;
        int f2_rows = f2_y1 - f2_y0;
        int f3_rows = f3_y1 - f3_y0;
        int out_rows = r1 - r0;

        dim3 blk(256);
        dim3 gr1(10, (f1_rows + 3) / 4);
        dim3 gr2(10, (f2_rows + 3) / 4);
        dim3 gr3(10, (f3_rows + 3) / 4);
        dim3 gr4(10, (out_rows + 3) / 4);

        // conv1: 6(->8 padded) -> 32, K=96 (12 taps, 3 zero)
        conv_mfma<8, 2, 3, false><<<gr1, blk, 0, stream>>>(
            xin, 0, HH, wp1, ap1, f1, f1_y0, f1_rows,
            nullptr, nullptr, nullptr);
        // conv2: 32 -> 32, K=288
        conv_mfma<32, 2, 9, false><<<gr2, blk, 0, stream>>>(
            f1, f1_y0, f1_rows, wp2, ap2, f2, f2_y0, f2_rows,
            nullptr, nullptr, nullptr);
        // conv3: 32 -> 16, K=288
        conv_mfma<32, 1, 9, false><<<gr3, blk, 0, stream>>>(
            f2, f2_y0, f2_rows, wp3, ap3, f3, f3_y0, f3_rows,
            nullptr, nullptr, nullptr);
        // final: 16 -> 4 (res0-2 + attn), K=160 (10 taps, 1 zero), fused blend
        conv_mfma<16, 1, 5, true><<<gr4, blk, 0, stream>>>(
            f3, f3_y0, f3_rows, wp4, ap4, nullptr, r0, out_rows,
            xb, st, (float*)d_out);
    }
}

// Round 6
// 378.256 us; speedup vs baseline: 2.0160x; 1.2033x over previous
//
#include <hip/hip_runtime.h>
#include <hip/hip_bf16.h>

#define HH 1080
#define WW 1920
#define HWSZ (HH * WW)

typedef __attribute__((ext_vector_type(8))) short bf16x8;
typedef __attribute__((ext_vector_type(4))) float f32x4;
typedef __attribute__((ext_vector_type(4))) short s16x4;

__device__ __forceinline__ float clipf(float x, float lo, float hi) {
    return fminf(fmaxf(x, lo), hi);
}
__device__ __forceinline__ short f2bf(float f) {
    __hip_bfloat16 h = __float2bfloat16(f);
    return *(short*)&h;
}
__device__ __forceinline__ float fpow(float a, float e) {
    return __expf(__logf(a) * e);   // a >= 1e-7 guaranteed by callers
}

// ---------------------------------------------------------------------------
// Kernel 1: classical grade + 3D LUT + blend.
// Writes: xb (planar f32) and xin (NHWC bf16 8ch: x0..2, xb0..2, 0, 0).
// ---------------------------------------------------------------------------
__global__ __launch_bounds__(256) void grade_kernel(
    const float* __restrict__ x, const float* __restrict__ lut,
    const float* __restrict__ cm, const float* __restrict__ cbp,
    const float* __restrict__ shp, const float* __restrict__ mip,
    const float* __restrict__ hip_, const float* __restrict__ cop,
    const float* __restrict__ satp, const float* __restrict__ wap,
    const float* __restrict__ lbp,
    float* __restrict__ xb, __hip_bfloat16* __restrict__ xin)
{
    int i = blockIdx.x * blockDim.x + threadIdx.x;
    if (i >= HWSZ) return;

    float in0 = x[i], in1 = x[HWSZ + i], in2 = x[2 * HWSZ + i];

    float M00 = clipf(cm[0], 0.9f, 1.1f), M01 = clipf(cm[1], 0.9f, 1.1f), M02 = clipf(cm[2], 0.9f, 1.1f);
    float M10 = clipf(cm[3], 0.9f, 1.1f), M11 = clipf(cm[4], 0.9f, 1.1f), M12 = clipf(cm[5], 0.9f, 1.1f);
    float M20 = clipf(cm[6], 0.9f, 1.1f), M21 = clipf(cm[7], 0.9f, 1.1f), M22 = clipf(cm[8], 0.9f, 1.1f);
    float bi0 = clipf(cbp[0], -0.02f, 0.02f);
    float bi1 = clipf(cbp[1], -0.02f, 0.02f);
    float bi2 = clipf(cbp[2], -0.02f, 0.02f);

    float sh  = clipf(shp[0], -0.02f, 0.05f);
    float mi  = clipf(mip[0], 0.95f, 1.05f);
    float hi  = clipf(hip_[0], 0.95f, 1.05f);
    float co  = clipf(cop[0], 0.98f, 1.05f);
    float sat = clipf(satp[0], 0.95f, 1.3f);
    float wa  = clipf(wap[0], -0.02f, 0.05f);
    float lb  = clipf(lbp[0], 0.7f, 0.9f);

    float xc[3];
    xc[0] = M00 * in0 + M01 * in1 + M02 * in2 + bi0;
    xc[1] = M10 * in0 + M11 * in1 + M12 * in2 + bi1;
    xc[2] = M20 * in0 + M21 * in1 + M22 * in2 + bi2;

    float inv_mi = 1.0f / mi, inv_co = 1.0f / co;
    float xg[3];
#pragma unroll
    for (int c = 0; c < 3; c++) {
        float v = xc[c];
        float sm = clipf(1.f - v, 0.f, 1.f);
        sm = sm * sm * sm;
        float xs = v + sh * sm * (1.f - v) * 0.5f;
        float xm = fpow(clipf(xs, 1e-7f, 1.f), inv_mi);
        float hm = clipf(xm, 0.f, 1.f);
        hm = hm * hm * hm;
        float x2 = clipf(xm * (1.f - hm * (1.f - hi) * 0.5f), 0.f, 1.f);
        xg[c] = fpow(clipf(x2, 1e-7f, 1.f), inv_co);
    }

    float luma = 0.299f * xg[0] + 0.587f * xg[1] + 0.114f * xg[2];
    float s0 = luma + sat * (xg[0] - luma);
    float s1 = luma + sat * (xg[1] - luma);
    float s2 = luma + sat * (xg[2] - luma);

    float pr = clipf(s0 * (1.f + wa), 0.f, 1.f);
    float pg = clipf(s1 * (1.f + wa * 0.3f), 0.f, 1.f);
    float pb = clipf(s2 * (1.f - wa * 0.5f), 0.f, 1.f);

    float cr = pr * 32.f, cg = pg * 32.f, cb2 = pb * 32.f;
    float fr = floorf(cr), fgq = floorf(cg), fb = floorf(cb2);
    float fx = cr - fr, fy = cg - fgq, fz = cb2 - fb;
    int x0 = min(max((int)fr, 0), 31);
    int y0 = min(max((int)fgq, 0), 31);
    int z0 = min(max((int)fb, 0), 31);

    const float* base = lut + ((x0 * 33 + y0) * 33 + z0) * 3;
    float pcl[3] = {pr, pg, pb};
    float bl[3];
#pragma unroll
    for (int ch = 0; ch < 3; ch++) {
        float c000 = base[ch];
        float c001 = base[3 + ch];
        float c010 = base[99 + ch];
        float c011 = base[102 + ch];
        float c100 = base[3267 + ch];
        float c101 = base[3270 + ch];
        float c110 = base[3366 + ch];
        float c111 = base[3369 + ch];
        float c00 = c000 * (1.f - fx) + c100 * fx;
        float c01 = c001 * (1.f - fx) + c101 * fx;
        float c10 = c010 * (1.f - fx) + c110 * fx;
        float c11 = c011 * (1.f - fx) + c111 * fx;
        float c0 = c00 * (1.f - fy) + c10 * fy;
        float c1 = c01 * (1.f - fy) + c11 * fy;
        float lv = c0 * (1.f - fz) + c1 * fz;
        bl[ch] = lb * lv + (1.f - lb) * pcl[ch];
        xb[(size_t)ch * HWSZ + i] = bl[ch];
    }

    bf16x8 xi;
    xi[0] = f2bf(in0); xi[1] = f2bf(in1); xi[2] = f2bf(in2);
    xi[3] = f2bf(bl[0]); xi[4] = f2bf(bl[1]); xi[5] = f2bf(bl[2]);
    xi[6] = 0; xi[7] = 0;
    *(bf16x8*)(xin + (size_t)i * 8) = xi;
}

// ---------------------------------------------------------------------------
// Pack kernel: fold BN into weights, emit per-lane MFMA A-fragments + acc-init.
// wp layout: frag (cb,g), lane l -> wp[((cb*NG+g)*64 + l)*8 + j]   (bf16)
// ap layout: (cb, lane l)       -> ap[(cb*64 + l)*4 + r]           (f32)
// ---------------------------------------------------------------------------
template <int CI, int CIR, int COUTB, int COUTR, int NG, bool FINAL>
__global__ __launch_bounds__(256) void pack_weights(
    const float* __restrict__ w, const float* __restrict__ w2,
    const float* __restrict__ bg, const float* __restrict__ bb,
    const float* __restrict__ bm, const float* __restrict__ bv,
    short* __restrict__ wp, float* __restrict__ ap)
{
    int t = blockIdx.x * blockDim.x + threadIdx.x;
    constexpr int NFRAG = COUTB * NG * 64;
    if (t < NFRAG) {
        int l    = t & 63;
        int frag = t >> 6;
        int g    = frag % NG;
        int cbk  = frag / NG;
        int mrow = l & 15;
        int sub  = l >> 4;
        int cout = cbk * 16 + mrow;
        float scl = 1.f;
        if (!FINAL)
            scl = (cout < COUTR) ? bg[cout] * rsqrtf(bv[cout] + 1e-5f) : 0.f;
        bf16x8 f;
#pragma unroll
        for (int j = 0; j < 8; j++) {
            int k   = g * 32 + sub * 8 + j;
            int tap = k / CI;
            int ci  = k % CI;
            float val = 0.f;
            if (tap < 9 && ci < CIR && cout < COUTR) {
                if (FINAL)
                    val = (cout < 3) ? w[(cout * CIR + ci) * 9 + tap]
                                     : w2[ci * 9 + tap];
                else
                    val = w[(cout * CIR + ci) * 9 + tap] * scl;
            }
            f[j] = f2bf(val);
        }
        *(bf16x8*)(wp + (size_t)t * 8) = f;
    } else if (t < NFRAG + COUTB * 64) {
        int u   = t - NFRAG;
        int l   = u & 63;
        int cbk = u >> 6;
        int sub = l >> 4;
        f32x4 a;
#pragma unroll
        for (int r = 0; r < 4; r++) {
            int c = cbk * 16 + sub * 4 + r;
            float v = 0.f;
            if (FINAL) {
                v = (c < 3) ? bb[c] : (c == 3 ? bm[0] : 0.f);
            } else if (c < COUTR) {
                float s = bg[c] * rsqrtf(bv[c] + 1e-5f);
                v = bb[c] - bm[c] * s;
            }
            a[r] = v;
        }
        *(f32x4*)(ap + (size_t)u * 4) = a;
    }
}

// ---------------------------------------------------------------------------
// Sliding-window MFMA conv for CI=32 (conv2/conv3). Each wave: one 16-px
// column tile, marches RPW=8 output rows. 9 tap fragments (dy,dx) in regs;
// per row: reuse 6, load 3 new (bottom row), issued one row-compute ahead.
// ---------------------------------------------------------------------------
template <int COUTB>
__global__ __launch_bounds__(256, 2) void conv_mfma32_slide(
    const __hip_bfloat16* __restrict__ in, int in_y0, int in_rows,
    const short* __restrict__ wp, const float* __restrict__ ap,
    __hip_bfloat16* __restrict__ out, int out_y0, int out_rows)
{
    constexpr int COUT = COUTB * 16;
    constexpr int RPW  = 8;

    int l    = threadIdx.x & 63;
    int wv   = threadIdx.x >> 6;
    int mrow = l & 15;
    int sub  = l >> 4;

    int xp = (blockIdx.x * 4 + wv) * 16 + mrow;   // this lane's pixel column
    int r0 = blockIdx.y * RPW;                    // strip start (local row)
    if (r0 >= out_rows) return;
    int y0 = out_y0 + r0;

    // Packed acc-init + weight fragments (coalesced dwordx4 loads).
    f32x4 ainit[COUTB];
#pragma unroll
    for (int cbk = 0; cbk < COUTB; cbk++)
        ainit[cbk] = *(const f32x4*)(ap + ((size_t)cbk * 64 + l) * 4);

    bf16x8 wf[COUTB][9];
#pragma unroll
    for (int cbk = 0; cbk < COUTB; cbk++)
#pragma unroll
        for (int g = 0; g < 9; g++)
            wf[cbk][g] = *(const bf16x8*)(wp + ((size_t)(cbk * 9 + g) * 64 + l) * 8);

    bool xl = xp > 0, xh = xp < WW - 1;
    const __hip_bfloat16* inb = in + sub * 8;

    // ROWLOAD: 3 dx fragments of data row yy (clamped into window; zero
    // outside the image).
#define ROWLOAD(yy, d0, d1, d2)                                              \
    do {                                                                     \
        int ybuf_ = min(max((yy) - in_y0, 0), in_rows - 1);                  \
        const __hip_bfloat16* rb_ = inb + (size_t)ybuf_ * (WW * 32);         \
        bool yok_ = (unsigned)(yy) < (unsigned)HH;                           \
        bf16x8 z_ = {0, 0, 0, 0, 0, 0, 0, 0};                                \
        d0 = (yok_ && xl) ? *(const bf16x8*)(rb_ + (size_t)(xp - 1) * 32) : z_; \
        d1 = yok_         ? *(const bf16x8*)(rb_ + (size_t)xp * 32)       : z_; \
        d2 = (yok_ && xh) ? *(const bf16x8*)(rb_ + (size_t)(xp + 1) * 32) : z_; \
    } while (0)

    bf16x8 t0, t1, t2, t3, t4, t5, t6, t7, t8;   // 9 live taps (dy-major)
    bf16x8 n0, n1, n2;                           // incoming bottom row
    ROWLOAD(y0 - 1, t0, t1, t2);
    ROWLOAD(y0,     t3, t4, t5);
    ROWLOAD(y0 + 1, t6, t7, t8);

#pragma unroll
    for (int r = 0; r < RPW; r++) {
        // Issue next bottom row early (consumed next iteration).
        if (r < RPW - 1) ROWLOAD(y0 + r + 2, n0, n1, n2);

        f32x4 acc[COUTB];
#pragma unroll
        for (int cbk = 0; cbk < COUTB; cbk++) acc[cbk] = ainit[cbk];
#pragma unroll
        for (int cbk = 0; cbk < COUTB; cbk++) {
            acc[cbk] = __builtin_amdgcn_mfma_f32_16x16x32_bf16(wf[cbk][0], t0, acc[cbk], 0, 0, 0);
            acc[cbk] = __builtin_amdgcn_mfma_f32_16x16x32_bf16(wf[cbk][1], t1, acc[cbk], 0, 0, 0);
            acc[cbk] = __builtin_amdgcn_mfma_f32_16x16x32_bf16(wf[cbk][2], t2, acc[cbk], 0, 0, 0);
            acc[cbk] = __builtin_amdgcn_mfma_f32_16x16x32_bf16(wf[cbk][3], t3, acc[cbk], 0, 0, 0);
            acc[cbk] = __builtin_amdgcn_mfma_f32_16x16x32_bf16(wf[cbk][4], t4, acc[cbk], 0, 0, 0);
            acc[cbk] = __builtin_amdgcn_mfma_f32_16x16x32_bf16(wf[cbk][5], t5, acc[cbk], 0, 0, 0);
            acc[cbk] = __builtin_amdgcn_mfma_f32_16x16x32_bf16(wf[cbk][6], t6, acc[cbk], 0, 0, 0);
            acc[cbk] = __builtin_amdgcn_mfma_f32_16x16x32_bf16(wf[cbk][7], t7, acc[cbk], 0, 0, 0);
            acc[cbk] = __builtin_amdgcn_mfma_f32_16x16x32_bf16(wf[cbk][8], t8, acc[cbk], 0, 0, 0);
        }

        int lrow = r0 + r;
        if (lrow < out_rows) {
#pragma unroll
            for (int cbk = 0; cbk < COUTB; cbk++) {
                s16x4 s_;
#pragma unroll
                for (int q = 0; q < 4; q++) s_[q] = f2bf(fmaxf(acc[cbk][q], 0.f));
                *(s16x4*)(out + ((size_t)lrow * WW + xp) * COUT + cbk * 16 + sub * 4) = s_;
            }
        }

        // Rotate window (register renaming under full unroll).
        if (r < RPW - 1) {
            t0 = t3; t1 = t4; t2 = t5;
            t3 = t6; t4 = t7; t5 = t8;
            t6 = n0; t7 = n1; t8 = n2;
        }
    }
#undef ROWLOAD
}

// ---------------------------------------------------------------------------
// Tile-pipelined MFMA conv (kept for conv1 CI=8 and FINAL CI=16).
// ---------------------------------------------------------------------------
template <int CI, int COUTB, int NG, bool FINAL>
__global__ __launch_bounds__(256, 2) void conv_mfma(
    const __hip_bfloat16* __restrict__ in, int in_y0, int in_rows,
    const short* __restrict__ wp, const float* __restrict__ ap,
    __hip_bfloat16* __restrict__ out, int out_y0, int out_rows,
    const float* __restrict__ xb, const float* __restrict__ stp,
    float* __restrict__ fout)
{
    constexpr int COUT = COUTB * 16;
    constexpr int SEGW = 192;
    constexpr int NT   = SEGW / 16;   // 12, even

    int l    = threadIdx.x & 63;
    int wv   = threadIdx.x >> 6;
    int lrow = blockIdx.y * 4 + wv;
    if (lrow >= out_rows) return;
    int y    = out_y0 + lrow;
    int x0   = blockIdx.x * SEGW;
    int mrow = l & 15;
    int sub  = l >> 4;

    f32x4 ainit[COUTB];
#pragma unroll
    for (int cbk = 0; cbk < COUTB; cbk++)
        ainit[cbk] = *(const f32x4*)(ap + ((size_t)cbk * 64 + l) * 4);

    bf16x8 wf[COUTB][NG];
#pragma unroll
    for (int cbk = 0; cbk < COUTB; cbk++)
#pragma unroll
        for (int g = 0; g < NG; g++)
            wf[cbk][g] = *(const bf16x8*)(wp + ((size_t)(cbk * NG + g) * 64 + l) * 8);

    float stv = 0.f;
    if (FINAL) stv = clipf(stp[0], 0.02f, 0.2f);

    const __hip_bfloat16* baseg[NG];
    int dxg[NG];
    bool okg[NG];
#pragma unroll
    for (int g = 0; g < NG; g++) {
        int kl  = g * 32 + sub * 8;
        int tap = kl / CI;
        int cib = kl % CI;
        int dy = (tap < 9) ? tap / 3 - 1 : 0;
        int dx = (tap < 9) ? tap % 3 - 1 : 0;
        int yy = y + dy;
        okg[g] = (yy >= 0 && yy < HH);
        baseg[g] = in + ((long)(yy - in_y0) * WW + dx) * CI + cib;
        dxg[g] = dx;
    }

#define LOADB(t, buf)                                                        \
    do {                                                                     \
        int xp_ = x0 + (t) * 16 + mrow;                                      \
        _Pragma("unroll")                                                    \
        for (int g = 0; g < NG; g++) {                                       \
            int xx_ = xp_ + dxg[g];                                          \
            bf16x8 v_ = {0, 0, 0, 0, 0, 0, 0, 0};                            \
            if (okg[g] && (unsigned)xx_ < (unsigned)WW)                      \
                v_ = *(const bf16x8*)(baseg[g] + (size_t)xp_ * CI);          \
            buf[g] = v_;                                                     \
        }                                                                    \
    } while (0)

#define COMPUTE(t, buf)                                                      \
    do {                                                                     \
        int xp_ = x0 + (t) * 16 + mrow;                                      \
        f32x4 acc[COUTB];                                                    \
        _Pragma("unroll")                                                    \
        for (int cbk = 0; cbk < COUTB; cbk++) acc[cbk] = ainit[cbk];         \
        _Pragma("unroll")                                                    \
        for (int g = 0; g < NG; g++) {                                       \
            _Pragma("unroll")                                                \
            for (int cbk = 0; cbk < COUTB; cbk++)                            \
                acc[cbk] = __builtin_amdgcn_mfma_f32_16x16x32_bf16(          \
                    wf[cbk][g], buf[g], acc[cbk], 0, 0, 0);                  \
        }                                                                    \
        if constexpr (!FINAL) {                                              \
            _Pragma("unroll")                                                \
            for (int cbk = 0; cbk < COUTB; cbk++) {                          \
                s16x4 s_;                                                    \
                _Pragma("unroll")                                            \
                for (int q = 0; q < 4; q++)                                  \
                    s_[q] = f2bf(fmaxf(acc[cbk][q], 0.f));                   \
                *(s16x4*)(out + ((size_t)lrow * WW + xp_) * COUT +           \
                          cbk * 16 + sub * 4) = s_;                          \
            }                                                                \
        } else {                                                             \
            if (sub == 0) {                                                  \
                float at_ = 1.f / (1.f + __expf(-acc[0][3]));                \
                size_t gi_ = (size_t)y * WW + xp_;                           \
                _Pragma("unroll")                                            \
                for (int c = 0; c < 3; c++) {                                \
                    float rs_ = tanhf(acc[0][c]);                            \
                    fout[(size_t)c * HWSZ + gi_] = clipf(                    \
                        xb[(size_t)c * HWSZ + gi_] + stv * rs_ * at_,        \
                        0.f, 1.f);                                           \
                }                                                            \
            }                                                                \
        }                                                                    \
    } while (0)

    bf16x8 bufA[NG], bufB[NG];
    LOADB(0, bufA);
#pragma unroll
    for (int tt = 0; tt < NT; tt += 2) {
        LOADB(tt + 1, bufB);
        COMPUTE(tt, bufA);
        if (tt + 2 < NT) LOADB(tt + 2, bufA);
        COMPUTE(tt + 1, bufB);
    }
#undef LOADB
#undef COMPUTE
}

// ---------------------------------------------------------------------------
extern "C" void kernel_launch(void* const* d_in, const int* in_sizes, int n_in,
                              void* d_out, int out_size, void* d_ws, size_t ws_size,
                              hipStream_t stream)
{
    const float* x   = (const float*)d_in[0];
    const float* lut = (const float*)d_in[1];
    const float* cm  = (const float*)d_in[2];
    const float* cb  = (const float*)d_in[3];
    const float* sh  = (const float*)d_in[4];
    const float* mi  = (const float*)d_in[5];
    const float* hi  = (const float*)d_in[6];
    const float* co  = (const float*)d_in[7];
    const float* sa  = (const float*)d_in[8];
    const float* wa  = (const float*)d_in[9];
    const float* lb  = (const float*)d_in[10];
    const float* st  = (const float*)d_in[11];
    const float* w1  = (const float*)d_in[12];
    const float* g1  = (const float*)d_in[13];
    const float* b1  = (const float*)d_in[14];
    const float* m1  = (const float*)d_in[15];
    const float* v1  = (const float*)d_in[16];
    const float* w2  = (const float*)d_in[17];
    const float* g2  = (const float*)d_in[18];
    const float* b2  = (const float*)d_in[19];
    const float* m2  = (const float*)d_in[20];
    const float* v2  = (const float*)d_in[21];
    const float* w3  = (const float*)d_in[22];
    const float* g3  = (const float*)d_in[23];
    const float* b3  = (const float*)d_in[24];
    const float* m3  = (const float*)d_in[25];
    const float* v3  = (const float*)d_in[26];
    const float* rw  = (const float*)d_in[27];
    const float* rb  = (const float*)d_in[28];
    const float* aw  = (const float*)d_in[29];
    const float* ab  = (const float*)d_in[30];

    // Workspace: xb f32 24.9MB | xin bf16 33.2MB | f1 66.7MB | f2 66.7MB | packs ~46KB
    char* ws = (char*)d_ws;
    const size_t XB_BYTES  = (size_t)3 * HWSZ * sizeof(float);
    const size_t XIN_BYTES = (size_t)8 * HWSZ * sizeof(__hip_bfloat16);
    const size_t F_BYTES   = (size_t)32 * 543 * WW * sizeof(__hip_bfloat16);
    float* xb = (float*)ws;
    __hip_bfloat16* xin = (__hip_bfloat16*)(ws + XB_BYTES);
    __hip_bfloat16* f1  = (__hip_bfloat16*)(ws + XB_BYTES + XIN_BYTES);
    __hip_bfloat16* f2  = (__hip_bfloat16*)(ws + XB_BYTES + XIN_BYTES + F_BYTES);
    __hip_bfloat16* f3  = f1;   // f1 dead once conv2 of this half is done

    char* pk = ws + XB_BYTES + XIN_BYTES + 2 * F_BYTES;
    short* wp1 = (short*)(pk);               // 6144 B
    float* ap1 = (float*)(pk + 6144);        // 2048 B
    short* wp2 = (short*)(pk + 8192);        // 18432 B
    float* ap2 = (float*)(pk + 26624);       // 2048 B
    short* wp3 = (short*)(pk + 28672);       // 9216 B
    float* ap3 = (float*)(pk + 37888);       // 1024 B
    short* wp4 = (short*)(pk + 38912);       // 5120 B
    float* ap4 = (float*)(pk + 44032);       // 1024 B

    pack_weights<8, 6, 2, 32, 3, false><<<2, 256, 0, stream>>>(
        w1, nullptr, g1, b1, m1, v1, wp1, ap1);
    pack_weights<32, 32, 2, 32, 9, false><<<5, 256, 0, stream>>>(
        w2, nullptr, g2, b2, m2, v2, wp2, ap2);
    pack_weights<32, 32, 1, 16, 9, false><<<3, 256, 0, stream>>>(
        w3, nullptr, g3, b3, m3, v3, wp3, ap3);
    pack_weights<16, 16, 1, 4, 5, true><<<2, 256, 0, stream>>>(
        rw, aw, rb, rb, ab, ab, wp4, ap4);

    {
        int grid = (HWSZ + 255) / 256;
        grade_kernel<<<grid, 256, 0, stream>>>(x, lut, cm, cb, sh, mi, hi, co,
                                               sa, wa, lb, xb, xin);
    }

    for (int h = 0; h < 2; h++) {
        int r0 = (h == 0) ? 0 : HH / 2;
        int r1 = (h == 0) ? HH / 2 : HH;

        int f1_y0 = max(r0 - 3, 0), f1_y1 = min(r1 + 3, HH);
        int f2_y0 = max(r0 - 2, 0), f2_y1 = min(r1 + 2, HH);
        int f3_y0 = max(r0 - 1, 0), f3_y1 = min(r1 + 1, HH);
        int f1_rows = f1_y1 - f1_y0;
        int f2_rows = f2_y1 - f2_y0;
        int f3_rows = f3_y1 - f3_y0;
        int out_rows = r1 - r0;

        dim3 blk(256);
        dim3 gr1(10, (f1_rows + 3) / 4);
        dim3 gr2s(30, (f2_rows + 7) / 8);   // slide: 30 x-blocks x strips
        dim3 gr3s(30, (f3_rows + 7) / 8);
        dim3 gr4(10, (out_rows + 3) / 4);

        // conv1: 6(->8 padded) -> 32, K=96 (12 taps, 3 zero)
        conv_mfma<8, 2, 3, false><<<gr1, blk, 0, stream>>>(
            xin, 0, HH, wp1, ap1, f1, f1_y0, f1_rows,
            nullptr, nullptr, nullptr);
        // conv2: 32 -> 32 (sliding window)
        conv_mfma32_slide<2><<<gr2s, blk, 0, stream>>>(
            f1, f1_y0, f1_rows, wp2, ap2, f2, f2_y0, f2_rows);
        // conv3: 32 -> 16 (sliding window)
        conv_mfma32_slide<1><<<gr3s, blk, 0, stream>>>(
            f2, f2_y0, f2_rows, wp3, ap3, f3, f3_y0, f3_rows);
        // final: 16 -> 4 (res0-2 + attn), K=160, fused blend
        conv_mfma<16, 1, 5, true><<<gr4, blk, 0, stream>>>(
            f3, f3_y0, f3_rows, wp4, ap4, nullptr, r0, out_rows,
            xb, st, (float*)d_out);
    }
}

// Round 8
// 334.720 us; speedup vs baseline: 2.2782x; 1.1301x over previous
//
#include <hip/hip_runtime.h>
#include <hip/hip_bf16.h>

#define HH 1080
#define WW 1920
#define HWSZ (HH * WW)

typedef __attribute__((ext_vector_type(8))) short bf16x8;
typedef __attribute__((ext_vector_type(4))) float f32x4;
typedef __attribute__((ext_vector_type(4))) short s16x4;

__device__ __forceinline__ float clipf(float x, float lo, float hi) {
    return fminf(fmaxf(x, lo), hi);
}
__device__ __forceinline__ short f2bf(float f) {
    __hip_bfloat16 h = __float2bfloat16(f);
    return *(short*)&h;
}
__device__ __forceinline__ float fpow(float a, float e) {
    return __expf(__logf(a) * e);   // a >= 1e-7 guaranteed by callers
}

// ---------------------------------------------------------------------------
// Kernel 1: classical grade + 3D LUT + blend.
// Writes: xb (planar f32) and xin (NHWC bf16 8ch: x0..2, xb0..2, 0, 0).
// ---------------------------------------------------------------------------
__global__ __launch_bounds__(256) void grade_kernel(
    const float* __restrict__ x, const float* __restrict__ lut,
    const float* __restrict__ cm, const float* __restrict__ cbp,
    const float* __restrict__ shp, const float* __restrict__ mip,
    const float* __restrict__ hip_, const float* __restrict__ cop,
    const float* __restrict__ satp, const float* __restrict__ wap,
    const float* __restrict__ lbp,
    float* __restrict__ xb, __hip_bfloat16* __restrict__ xin)
{
    int i = blockIdx.x * blockDim.x + threadIdx.x;
    if (i >= HWSZ) return;

    float in0 = x[i], in1 = x[HWSZ + i], in2 = x[2 * HWSZ + i];

    float M00 = clipf(cm[0], 0.9f, 1.1f), M01 = clipf(cm[1], 0.9f, 1.1f), M02 = clipf(cm[2], 0.9f, 1.1f);
    float M10 = clipf(cm[3], 0.9f, 1.1f), M11 = clipf(cm[4], 0.9f, 1.1f), M12 = clipf(cm[5], 0.9f, 1.1f);
    float M20 = clipf(cm[6], 0.9f, 1.1f), M21 = clipf(cm[7], 0.9f, 1.1f), M22 = clipf(cm[8], 0.9f, 1.1f);
    float bi0 = clipf(cbp[0], -0.02f, 0.02f);
    float bi1 = clipf(cbp[1], -0.02f, 0.02f);
    float bi2 = clipf(cbp[2], -0.02f, 0.02f);

    float sh  = clipf(shp[0], -0.02f, 0.05f);
    float mi  = clipf(mip[0], 0.95f, 1.05f);
    float hi  = clipf(hip_[0], 0.95f, 1.05f);
    float co  = clipf(cop[0], 0.98f, 1.05f);
    float sat = clipf(satp[0], 0.95f, 1.3f);
    float wa  = clipf(wap[0], -0.02f, 0.05f);
    float lb  = clipf(lbp[0], 0.7f, 0.9f);

    float xc[3];
    xc[0] = M00 * in0 + M01 * in1 + M02 * in2 + bi0;
    xc[1] = M10 * in0 + M11 * in1 + M12 * in2 + bi1;
    xc[2] = M20 * in0 + M21 * in1 + M22 * in2 + bi2;

    float inv_mi = 1.0f / mi, inv_co = 1.0f / co;
    float xg[3];
#pragma unroll
    for (int c = 0; c < 3; c++) {
        float v = xc[c];
        float sm = clipf(1.f - v, 0.f, 1.f);
        sm = sm * sm * sm;
        float xs = v + sh * sm * (1.f - v) * 0.5f;
        float xm = fpow(clipf(xs, 1e-7f, 1.f), inv_mi);
        float hm = clipf(xm, 0.f, 1.f);
        hm = hm * hm * hm;
        float x2 = clipf(xm * (1.f - hm * (1.f - hi) * 0.5f), 0.f, 1.f);
        xg[c] = fpow(clipf(x2, 1e-7f, 1.f), inv_co);
    }

    float luma = 0.299f * xg[0] + 0.587f * xg[1] + 0.114f * xg[2];
    float s0 = luma + sat * (xg[0] - luma);
    float s1 = luma + sat * (xg[1] - luma);
    float s2 = luma + sat * (xg[2] - luma);

    float pr = clipf(s0 * (1.f + wa), 0.f, 1.f);
    float pg = clipf(s1 * (1.f + wa * 0.3f), 0.f, 1.f);
    float pb = clipf(s2 * (1.f - wa * 0.5f), 0.f, 1.f);

    float cr = pr * 32.f, cg = pg * 32.f, cb2 = pb * 32.f;
    float fr = floorf(cr), fgq = floorf(cg), fb = floorf(cb2);
    float fx = cr - fr, fy = cg - fgq, fz = cb2 - fb;
    int x0 = min(max((int)fr, 0), 31);
    int y0 = min(max((int)fgq, 0), 31);
    int z0 = min(max((int)fb, 0), 31);

    const float* base = lut + ((x0 * 33 + y0) * 33 + z0) * 3;
    float pcl[3] = {pr, pg, pb};
    float bl[3];
#pragma unroll
    for (int ch = 0; ch < 3; ch++) {
        float c000 = base[ch];
        float c001 = base[3 + ch];
        float c010 = base[99 + ch];
        float c011 = base[102 + ch];
        float c100 = base[3267 + ch];
        float c101 = base[3270 + ch];
        float c110 = base[3366 + ch];
        float c111 = base[3369 + ch];
        float c00 = c000 * (1.f - fx) + c100 * fx;
        float c01 = c001 * (1.f - fx) + c101 * fx;
        float c10 = c010 * (1.f - fx) + c110 * fx;
        float c11 = c011 * (1.f - fx) + c111 * fx;
        float c0 = c00 * (1.f - fy) + c10 * fy;
        float c1 = c01 * (1.f - fy) + c11 * fy;
        float lv = c0 * (1.f - fz) + c1 * fz;
        bl[ch] = lb * lv + (1.f - lb) * pcl[ch];
        xb[(size_t)ch * HWSZ + i] = bl[ch];
    }

    bf16x8 xi;
    xi[0] = f2bf(in0); xi[1] = f2bf(in1); xi[2] = f2bf(in2);
    xi[3] = f2bf(bl[0]); xi[4] = f2bf(bl[1]); xi[5] = f2bf(bl[2]);
    xi[6] = 0; xi[7] = 0;
    *(bf16x8*)(xin + (size_t)i * 8) = xi;
}

// ---------------------------------------------------------------------------
// Pack kernel: fold BN into weights, emit per-lane MFMA A-fragments + acc-init.
// wp layout: frag (cb,g), lane l -> wp[((cb*NG+g)*64 + l)*8 + j]   (bf16)
// ap layout: (cb, lane l)       -> ap[(cb*64 + l)*4 + r]           (f32)
// ---------------------------------------------------------------------------
template <int CI, int CIR, int COUTB, int COUTR, int NG, bool FINAL>
__global__ __launch_bounds__(256) void pack_weights(
    const float* __restrict__ w, const float* __restrict__ w2,
    const float* __restrict__ bg, const float* __restrict__ bb,
    const float* __restrict__ bm, const float* __restrict__ bv,
    short* __restrict__ wp, float* __restrict__ ap)
{
    int t = blockIdx.x * blockDim.x + threadIdx.x;
    constexpr int NFRAG = COUTB * NG * 64;
    if (t < NFRAG) {
        int l    = t & 63;
        int frag = t >> 6;
        int g    = frag % NG;
        int cbk  = frag / NG;
        int mrow = l & 15;
        int sub  = l >> 4;
        int cout = cbk * 16 + mrow;
        float scl = 1.f;
        if (!FINAL)
            scl = (cout < COUTR) ? bg[cout] * rsqrtf(bv[cout] + 1e-5f) : 0.f;
        bf16x8 f;
#pragma unroll
        for (int j = 0; j < 8; j++) {
            int k   = g * 32 + sub * 8 + j;
            int tap = k / CI;
            int ci  = k % CI;
            float val = 0.f;
            if (tap < 9 && ci < CIR && cout < COUTR) {
                if (FINAL)
                    val = (cout < 3) ? w[(cout * CIR + ci) * 9 + tap]
                                     : w2[ci * 9 + tap];
                else
                    val = w[(cout * CIR + ci) * 9 + tap] * scl;
            }
            f[j] = f2bf(val);
        }
        *(bf16x8*)(wp + (size_t)t * 8) = f;
    } else if (t < NFRAG + COUTB * 64) {
        int u   = t - NFRAG;
        int l   = u & 63;
        int cbk = u >> 6;
        int sub = l >> 4;
        f32x4 a;
#pragma unroll
        for (int r = 0; r < 4; r++) {
            int c = cbk * 16 + sub * 4 + r;
            float v = 0.f;
            if (FINAL) {
                v = (c < 3) ? bb[c] : (c == 3 ? bm[0] : 0.f);
            } else if (c < COUTR) {
                float s = bg[c] * rsqrtf(bv[c] + 1e-5f);
                v = bb[c] - bm[c] * s;
            }
            a[r] = v;
        }
        *(f32x4*)(ap + (size_t)u * 4) = a;
    }
}

// ---------------------------------------------------------------------------
// Sliding-window MFMA conv for CI=32 (conv2/conv3). Each wave: one 16-px
// column tile, marches RPW=16 output rows. 9 tap fragments (dy,dx) in regs;
// per row: reuse 6, load 3 new (bottom row), issued one row-compute ahead.
// ---------------------------------------------------------------------------
template <int COUTB>
__global__ __launch_bounds__(256, 2) void conv_mfma32_slide(
    const __hip_bfloat16* __restrict__ in, int in_y0, int in_rows,
    const short* __restrict__ wp, const float* __restrict__ ap,
    __hip_bfloat16* __restrict__ out, int out_y0, int out_rows)
{
    constexpr int COUT = COUTB * 16;
    constexpr int RPW  = 16;

    int l    = threadIdx.x & 63;
    int wv   = threadIdx.x >> 6;
    int mrow = l & 15;
    int sub  = l >> 4;

    int xp = (blockIdx.x * 4 + wv) * 16 + mrow;   // this lane's pixel column
    int r0 = blockIdx.y * RPW;                    // strip start (local row)
    if (r0 >= out_rows) return;
    int y0 = out_y0 + r0;

    // Packed acc-init + weight fragments (coalesced dwordx4 loads).
    f32x4 ainit[COUTB];
#pragma unroll
    for (int cbk = 0; cbk < COUTB; cbk++)
        ainit[cbk] = *(const f32x4*)(ap + ((size_t)cbk * 64 + l) * 4);

    bf16x8 wf[COUTB][9];
#pragma unroll
    for (int cbk = 0; cbk < COUTB; cbk++)
#pragma unroll
        for (int g = 0; g < 9; g++)
            wf[cbk][g] = *(const bf16x8*)(wp + ((size_t)(cbk * 9 + g) * 64 + l) * 8);

    bool xl = xp > 0, xh = xp < WW - 1;
    const __hip_bfloat16* inb = in + sub * 8;

    // ROWLOAD: 3 dx fragments of data row yy (clamped into window; zero
    // outside the image).
#define ROWLOAD(yy, d0, d1, d2)                                              \
    do {                                                                     \
        int ybuf_ = min(max((yy) - in_y0, 0), in_rows - 1);                  \
        const __hip_bfloat16* rb_ = inb + (size_t)ybuf_ * (WW * 32);         \
        bool yok_ = (unsigned)(yy) < (unsigned)HH;                           \
        bf16x8 z_ = {0, 0, 0, 0, 0, 0, 0, 0};                                \
        d0 = (yok_ && xl) ? *(const bf16x8*)(rb_ + (size_t)(xp - 1) * 32) : z_; \
        d1 = yok_         ? *(const bf16x8*)(rb_ + (size_t)xp * 32)       : z_; \
        d2 = (yok_ && xh) ? *(const bf16x8*)(rb_ + (size_t)(xp + 1) * 32) : z_; \
    } while (0)

    bf16x8 t0, t1, t2, t3, t4, t5, t6, t7, t8;   // 9 live taps (dy-major)
    bf16x8 n0, n1, n2;                           // incoming bottom row
    ROWLOAD(y0 - 1, t0, t1, t2);
    ROWLOAD(y0,     t3, t4, t5);
    ROWLOAD(y0 + 1, t6, t7, t8);

#pragma unroll
    for (int r = 0; r < RPW; r++) {
        // Issue next bottom row early (consumed next iteration).
        if (r < RPW - 1) ROWLOAD(y0 + r + 2, n0, n1, n2);

        f32x4 acc[COUTB];
#pragma unroll
        for (int cbk = 0; cbk < COUTB; cbk++) acc[cbk] = ainit[cbk];
#pragma unroll
        for (int cbk = 0; cbk < COUTB; cbk++) {
            acc[cbk] = __builtin_amdgcn_mfma_f32_16x16x32_bf16(wf[cbk][0], t0, acc[cbk], 0, 0, 0);
            acc[cbk] = __builtin_amdgcn_mfma_f32_16x16x32_bf16(wf[cbk][1], t1, acc[cbk], 0, 0, 0);
            acc[cbk] = __builtin_amdgcn_mfma_f32_16x16x32_bf16(wf[cbk][2], t2, acc[cbk], 0, 0, 0);
            acc[cbk] = __builtin_amdgcn_mfma_f32_16x16x32_bf16(wf[cbk][3], t3, acc[cbk], 0, 0, 0);
            acc[cbk] = __builtin_amdgcn_mfma_f32_16x16x32_bf16(wf[cbk][4], t4, acc[cbk], 0, 0, 0);
            acc[cbk] = __builtin_amdgcn_mfma_f32_16x16x32_bf16(wf[cbk][5], t5, acc[cbk], 0, 0, 0);
            acc[cbk] = __builtin_amdgcn_mfma_f32_16x16x32_bf16(wf[cbk][6], t6, acc[cbk], 0, 0, 0);
            acc[cbk] = __builtin_amdgcn_mfma_f32_16x16x32_bf16(wf[cbk][7], t7, acc[cbk], 0, 0, 0);
            acc[cbk] = __builtin_amdgcn_mfma_f32_16x16x32_bf16(wf[cbk][8], t8, acc[cbk], 0, 0, 0);
        }

        int lrow = r0 + r;
        if (lrow < out_rows) {
#pragma unroll
            for (int cbk = 0; cbk < COUTB; cbk++) {
                s16x4 s_;
#pragma unroll
                for (int q = 0; q < 4; q++) s_[q] = f2bf(fmaxf(acc[cbk][q], 0.f));
                *(s16x4*)(out + ((size_t)lrow * WW + xp) * COUT + cbk * 16 + sub * 4) = s_;
            }
        }

        // Rotate window (register renaming under full unroll).
        if (r < RPW - 1) {
            t0 = t3; t1 = t4; t2 = t5;
            t3 = t6; t4 = t7; t5 = t8;
            t6 = n0; t7 = n1; t8 = n2;
        }
    }
#undef ROWLOAD
}

// ---------------------------------------------------------------------------
// Tile-pipelined MFMA conv (conv1 CI=8 and FINAL CI=16).
// FINAL epilogue is wave-parallel: shuffles redistribute the 4 result rows
// (lanes 0-15) so each of 64 lanes does exactly one transcendental.
// ---------------------------------------------------------------------------
template <int CI, int COUTB, int NG, bool FINAL>
__global__ __launch_bounds__(256, 2) void conv_mfma(
    const __hip_bfloat16* __restrict__ in, int in_y0, int in_rows,
    const short* __restrict__ wp, const float* __restrict__ ap,
    __hip_bfloat16* __restrict__ out, int out_y0, int out_rows,
    const float* __restrict__ xb, const float* __restrict__ stp,
    float* __restrict__ fout)
{
    constexpr int COUT = COUTB * 16;
    constexpr int SEGW = 192;
    constexpr int NT   = SEGW / 16;   // 12, even

    int l    = threadIdx.x & 63;
    int wv   = threadIdx.x >> 6;
    int lrow = blockIdx.y * 4 + wv;
    if (lrow >= out_rows) return;
    int y    = out_y0 + lrow;
    int x0   = blockIdx.x * SEGW;
    int mrow = l & 15;
    int sub  = l >> 4;

    f32x4 ainit[COUTB];
#pragma unroll
    for (int cbk = 0; cbk < COUTB; cbk++)
        ainit[cbk] = *(const f32x4*)(ap + ((size_t)cbk * 64 + l) * 4);

    bf16x8 wf[COUTB][NG];
#pragma unroll
    for (int cbk = 0; cbk < COUTB; cbk++)
#pragma unroll
        for (int g = 0; g < NG; g++)
            wf[cbk][g] = *(const bf16x8*)(wp + ((size_t)(cbk * NG + g) * 64 + l) * 8);

    float stv = 0.f;
    if (FINAL) stv = clipf(stp[0], 0.02f, 0.2f);

    const __hip_bfloat16* baseg[NG];
    int dxg[NG];
    bool okg[NG];
#pragma unroll
    for (int g = 0; g < NG; g++) {
        int kl  = g * 32 + sub * 8;
        int tap = kl / CI;
        int cib = kl % CI;
        int dy = (tap < 9) ? tap / 3 - 1 : 0;
        int dx = (tap < 9) ? tap % 3 - 1 : 0;
        int yy = y + dy;
        okg[g] = (yy >= 0 && yy < HH);
        baseg[g] = in + ((long)(yy - in_y0) * WW + dx) * CI + cib;
        dxg[g] = dx;
    }

#define LOADB(t, buf)                                                        \
    do {                                                                     \
        int xp_ = x0 + (t) * 16 + mrow;                                      \
        _Pragma("unroll")                                                    \
        for (int g = 0; g < NG; g++) {                                       \
            int xx_ = xp_ + dxg[g];                                          \
            bf16x8 v_ = {0, 0, 0, 0, 0, 0, 0, 0};                            \
            if (okg[g] && (unsigned)xx_ < (unsigned)WW)                      \
                v_ = *(const bf16x8*)(baseg[g] + (size_t)xp_ * CI);          \
            buf[g] = v_;                                                     \
        }                                                                    \
    } while (0)

#define COMPUTE(t, buf)                                                      \
    do {                                                                     \
        int xp_ = x0 + (t) * 16 + mrow;                                      \
        float xbv_ = 0.f;                                                    \
        if (FINAL && sub < 3)                                                \
            xbv_ = xb[(size_t)sub * HWSZ + (size_t)y * WW + xp_];            \
        f32x4 acc[COUTB];                                                    \
        _Pragma("unroll")                                                    \
        for (int cbk = 0; cbk < COUTB; cbk++) acc[cbk] = ainit[cbk];         \
        _Pragma("unroll")                                                    \
        for (int g = 0; g < NG; g++) {                                       \
            _Pragma("unroll")                                                \
            for (int cbk = 0; cbk < COUTB; cbk++)                            \
                acc[cbk] = __builtin_amdgcn_mfma_f32_16x16x32_bf16(          \
                    wf[cbk][g], buf[g], acc[cbk], 0, 0, 0);                  \
        }                                                                    \
        if constexpr (!FINAL) {                                              \
            _Pragma("unroll")                                                \
            for (int cbk = 0; cbk < COUTB; cbk++) {                          \
                s16x4 s_;                                                    \
                _Pragma("unroll")                                            \
                for (int q = 0; q < 4; q++)                                  \
                    s_[q] = f2bf(fmaxf(acc[cbk][q], 0.f));                   \
                *(s16x4*)(out + ((size_t)lrow * WW + xp_) * COUT +           \
                          cbk * 16 + sub * 4) = s_;                          \
            }                                                                \
        } else {                                                             \
            /* redistribute rows 0-3 (lanes 0-15) across the wave */         \
            float bc0_ = __shfl(acc[0][0], mrow);                            \
            float bc1_ = __shfl(acc[0][1], mrow);                            \
            float bc2_ = __shfl(acc[0][2], mrow);                            \
            float bc3_ = __shfl(acc[0][3], mrow);                            \
            float mv_ = (sub == 0) ? bc0_ : (sub == 1) ? bc1_                \
                      : (sub == 2) ? bc2_ : bc3_;                            \
            float e_  = __expf((sub == 3) ? -mv_ : 2.f * mv_);               \
            float tv_ = (sub == 3) ? 1.f / (1.f + e_)                        \
                                   : 1.f - 2.f / (1.f + e_);                 \
            float atv_ = __shfl(tv_, 48 + mrow);                             \
            if (sub < 3) {                                                   \
                size_t off_ = (size_t)sub * HWSZ + (size_t)y * WW + xp_;     \
                fout[off_] = clipf(xbv_ + stv * tv_ * atv_, 0.f, 1.f);       \
            }                                                                \
        }                                                                    \
    } while (0)

    bf16x8 bufA[NG], bufB[NG];
    LOADB(0, bufA);
#pragma unroll
    for (int tt = 0; tt < NT; tt += 2) {
        LOADB(tt + 1, bufB);
        COMPUTE(tt, bufA);
        if (tt + 2 < NT) LOADB(tt + 2, bufA);
        COMPUTE(tt + 1, bufB);
    }
#undef LOADB
#undef COMPUTE
}

// ---------------------------------------------------------------------------
extern "C" void kernel_launch(void* const* d_in, const int* in_sizes, int n_in,
                              void* d_out, int out_size, void* d_ws, size_t ws_size,
                              hipStream_t stream)
{
    const float* x   = (const float*)d_in[0];
    const float* lut = (const float*)d_in[1];
    const float* cm  = (const float*)d_in[2];
    const float* cb  = (const float*)d_in[3];
    const float* sh  = (const float*)d_in[4];
    const float* mi  = (const float*)d_in[5];
    const float* hi  = (const float*)d_in[6];
    const float* co  = (const float*)d_in[7];
    const float* sa  = (const float*)d_in[8];
    const float* wa  = (const float*)d_in[9];
    const float* lb  = (const float*)d_in[10];
    const float* st  = (const float*)d_in[11];
    const float* w1  = (const float*)d_in[12];
    const float* g1  = (const float*)d_in[13];
    const float* b1  = (const float*)d_in[14];
    const float* m1  = (const float*)d_in[15];
    const float* v1  = (const float*)d_in[16];
    const float* w2  = (const float*)d_in[17];
    const float* g2  = (const float*)d_in[18];
    const float* b2  = (const float*)d_in[19];
    const float* m2  = (const float*)d_in[20];
    const float* v2  = (const float*)d_in[21];
    const float* w3  = (const float*)d_in[22];
    const float* g3  = (const float*)d_in[23];
    const float* b3  = (const float*)d_in[24];
    const float* m3  = (const float*)d_in[25];
    const float* v3  = (const float*)d_in[26];
    const float* rw  = (const float*)d_in[27];
    const float* rb  = (const float*)d_in[28];
    const float* aw  = (const float*)d_in[29];
    const float* ab  = (const float*)d_in[30];

    // Workspace: xb f32 24.9MB | xin bf16 33.2MB | f1 66.7MB | f2 66.7MB | packs ~46KB
    char* ws = (char*)d_ws;
    const size_t XB_BYTES  = (size_t)3 * HWSZ * sizeof(float);
    const size_t XIN_BYTES = (size_t)8 * HWSZ * sizeof(__hip_bfloat16);
    const size_t F_BYTES   = (size_t)32 * 543 * WW * sizeof(__hip_bfloat16);
    float* xb = (float*)ws;
    __hip_bfloat16* xin = (__hip_bfloat16*)(ws + XB_BYTES);
    __hip_bfloat16* f1  = (__hip_bfloat16*)(ws + XB_BYTES + XIN_BYTES);
    __hip_bfloat16* f2  = (__hip_bfloat16*)(ws + XB_BYTES + XIN_BYTES + F_BYTES);
    __hip_bfloat16* f3  = f1;   // f1 dead once conv2 of this half is done

    char* pk = ws + XB_BYTES + XIN_BYTES + 2 * F_BYTES;
    short* wp1 = (short*)(pk);               // 6144 B
    float* ap1 = (float*)(pk + 6144);        // 2048 B
    short* wp2 = (short*)(pk + 8192);        // 18432 B
    float* ap2 = (float*)(pk + 26624);       // 2048 B
    short* wp3 = (short*)(pk + 28672);       // 9216 B
    float* ap3 = (float*)(pk + 37888);       // 1024 B
    short* wp4 = (short*)(pk + 38912);       // 5120 B
    float* ap4 = (float*)(pk + 44032);       // 1024 B

    pack_weights<8, 6, 2, 32, 3, false><<<2, 256, 0, stream>>>(
        w1, nullptr, g1, b1, m1, v1, wp1, ap1);
    pack_weights<32, 32, 2, 32, 9, false><<<5, 256, 0, stream>>>(
        w2, nullptr, g2, b2, m2, v2, wp2, ap2);
    pack_weights<32, 32, 1, 16, 9, false><<<3, 256, 0, stream>>>(
        w3, nullptr, g3, b3, m3, v3, wp3, ap3);
    pack_weights<16, 16, 1, 4, 5, true><<<2, 256, 0, stream>>>(
        rw, aw, rb, rb, ab, ab, wp4, ap4);

    {
        int grid = (HWSZ + 255) / 256;
        grade_kernel<<<grid, 256, 0, stream>>>(x, lut, cm, cb, sh, mi, hi, co,
                                               sa, wa, lb, xb, xin);
    }

    for (int h = 0; h < 2; h++) {
        int r0 = (h == 0) ? 0 : HH / 2;
        int r1 = (h == 0) ? HH / 2 : HH;

        int f1_y0 = max(r0 - 3, 0), f1_y1 = min(r1 + 3, HH);
        int f2_y0 = max(r0 - 2, 0), f2_y1 = min(r1 + 2, HH);
        int f3_y0 = max(r0 - 1, 0), f3_y1 = min(r1 + 1, HH);
        int f1_rows = f1_y1 - f1_y0;
        int f2_rows = f2_y1 - f2_y0;
        int f3_rows = f3_y1 - f3_y0;
        int out_rows = r1 - r0;

        dim3 blk(256);
        dim3 gr1(10, (f1_rows + 3) / 4);
        dim3 gr2s(30, (f2_rows + 15) / 16);   // slide: RPW=16 strips
        dim3 gr3s(30, (f3_rows + 15) / 16);
        dim3 gr4(10, (out_rows + 3) / 4);

        // conv1: 6(->8 padded) -> 32, K=96 (12 taps, 3 zero)
        conv_mfma<8, 2, 3, false><<<gr1, blk, 0, stream>>>(
            xin, 0, HH, wp1, ap1, f1, f1_y0, f1_rows,
            nullptr, nullptr, nullptr);
        // conv2: 32 -> 32 (sliding window)
        conv_mfma32_slide<2><<<gr2s, blk, 0, stream>>>(
            f1, f1_y0, f1_rows, wp2, ap2, f2, f2_y0, f2_rows);
        // conv3: 32 -> 16 (sliding window)
        conv_mfma32_slide<1><<<gr3s, blk, 0, stream>>>(
            f2, f2_y0, f2_rows, wp3, ap3, f3, f3_y0, f3_rows);
        // final: 16 -> 4 (res0-2 + attn), K=160, fused blend + wave-parallel
        // epilogue
        conv_mfma<16, 1, 5, true><<<gr4, blk, 0, stream>>>(
            f3, f3_y0, f3_rows, wp4, ap4, nullptr, r0, out_rows,
            xb, st, (float*)d_out);
    }
}